// Round 1
// baseline (161.926 us; speedup 1.0000x reference)
//
#include <hip/hip_runtime.h>

#define EDIM 128
#define MNBR 16

// ---------------------------------------------------------------------------
// K1: h1[n] = mean over 16 neighbors of emb[nbr] ; 8 nodes/block, 32 lanes/node,
//     float4 per lane (32*4 = 128 floats). Coalesced 512B row reads.
// ---------------------------------------------------------------------------
__global__ __launch_bounds__(256) void hop_mean_kernel(
    const int* __restrict__ nbr, const float* __restrict__ src,
    float* __restrict__ dst, int nNodes) {
  int node = blockIdx.x * 8 + (threadIdx.x >> 5);
  if (node >= nNodes) return;
  int lane = threadIdx.x & 31;

  const int4* nb4 = reinterpret_cast<const int4*>(nbr) + (size_t)node * 4;
  int4 a = nb4[0], b = nb4[1], c = nb4[2], d = nb4[3];
  int idx[16] = {a.x, a.y, a.z, a.w, b.x, b.y, b.z, b.w,
                 c.x, c.y, c.z, c.w, d.x, d.y, d.z, d.w};

  float4 acc0 = make_float4(0.f, 0.f, 0.f, 0.f);
  float4 acc1 = make_float4(0.f, 0.f, 0.f, 0.f);
#pragma unroll
  for (int m = 0; m < 16; m += 2) {
    float4 v0 = *reinterpret_cast<const float4*>(src + (size_t)idx[m] * EDIM + lane * 4);
    float4 v1 = *reinterpret_cast<const float4*>(src + (size_t)idx[m + 1] * EDIM + lane * 4);
    acc0.x += v0.x; acc0.y += v0.y; acc0.z += v0.z; acc0.w += v0.w;
    acc1.x += v1.x; acc1.y += v1.y; acc1.z += v1.z; acc1.w += v1.w;
  }
  float4 r;
  r.x = (acc0.x + acc1.x) * 0.0625f;
  r.y = (acc0.y + acc1.y) * 0.0625f;
  r.z = (acc0.z + acc1.z) * 0.0625f;
  r.w = (acc0.w + acc1.w) * 0.0625f;
  *reinterpret_cast<float4*>(dst + (size_t)node * EDIM + lane * 4) = r;
}

// ---------------------------------------------------------------------------
// K2: X[b] = mean over 16 neighbors-of-inputs[b] of h1[..]  + emb[inputs[b]]
// ---------------------------------------------------------------------------
__global__ __launch_bounds__(256) void gather2_kernel(
    const int* __restrict__ inputs, const int* __restrict__ nbr,
    const float* __restrict__ h1, const float* __restrict__ emb,
    float* __restrict__ X, int Bn) {
  int b = blockIdx.x * 8 + (threadIdx.x >> 5);
  if (b >= Bn) return;
  int lane = threadIdx.x & 31;
  int node = inputs[b];

  const int4* nb4 = reinterpret_cast<const int4*>(nbr) + (size_t)node * 4;
  int4 aa = nb4[0], bb = nb4[1], cc = nb4[2], dd = nb4[3];
  int idx[16] = {aa.x, aa.y, aa.z, aa.w, bb.x, bb.y, bb.z, bb.w,
                 cc.x, cc.y, cc.z, cc.w, dd.x, dd.y, dd.z, dd.w};

  float4 acc0 = make_float4(0.f, 0.f, 0.f, 0.f);
  float4 acc1 = make_float4(0.f, 0.f, 0.f, 0.f);
#pragma unroll
  for (int m = 0; m < 16; m += 2) {
    float4 v0 = *reinterpret_cast<const float4*>(h1 + (size_t)idx[m] * EDIM + lane * 4);
    float4 v1 = *reinterpret_cast<const float4*>(h1 + (size_t)idx[m + 1] * EDIM + lane * 4);
    acc0.x += v0.x; acc0.y += v0.y; acc0.z += v0.z; acc0.w += v0.w;
    acc1.x += v1.x; acc1.y += v1.y; acc1.z += v1.z; acc1.w += v1.w;
  }
  float4 se = *reinterpret_cast<const float4*>(emb + (size_t)node * EDIM + lane * 4);
  float4 r;
  r.x = (acc0.x + acc1.x) * 0.0625f + se.x;
  r.y = (acc0.y + acc1.y) * 0.0625f + se.y;
  r.z = (acc0.z + acc1.z) * 0.0625f + se.z;
  r.w = (acc0.w + acc1.w) * 0.0625f + se.w;
  *reinterpret_cast<float4*>(X + (size_t)b * EDIM + lane * 4) = r;
}

// ---------------------------------------------------------------------------
// K3: out = relu(X @ W^T + bias).  X:[B,128], W:[F,128], out:[B,F].
// 64x64 output tile/block, 256 threads, 4x4 per thread, K=128 staged
// transposed in LDS (stride 68 floats keeps float4 alignment).
// ---------------------------------------------------------------------------
__global__ __launch_bounds__(256) void gemm_relu_kernel(
    const float* __restrict__ X, const float* __restrict__ W,
    const float* __restrict__ bias, float* __restrict__ out, int Fdim) {
  __shared__ float Xs[128][68];  // [k][row]
  __shared__ float Ws[128][68];  // [k][col]

  int tid = threadIdx.x;
  int lane = tid & 63;
  int wid = tid >> 6;  // 0..3
  int brow0 = blockIdx.x * 64;
  int bcol0 = blockIdx.y * 64;

  // Stage tiles transposed: thread loads float4 (4 consecutive k) of one row,
  // scatters to Xs[k][row]. LDS writes are lane-consecutive -> conflict-free.
#pragma unroll
  for (int i = 0; i < 8; ++i) {
    int c4 = i * 4 + wid;  // 0..31 (float4 index along K)
    float4 v = *reinterpret_cast<const float4*>(X + (size_t)(brow0 + lane) * EDIM + c4 * 4);
    Xs[c4 * 4 + 0][lane] = v.x;
    Xs[c4 * 4 + 1][lane] = v.y;
    Xs[c4 * 4 + 2][lane] = v.z;
    Xs[c4 * 4 + 3][lane] = v.w;
    float4 w = *reinterpret_cast<const float4*>(W + (size_t)(bcol0 + lane) * EDIM + c4 * 4);
    Ws[c4 * 4 + 0][lane] = w.x;
    Ws[c4 * 4 + 1][lane] = w.y;
    Ws[c4 * 4 + 2][lane] = w.z;
    Ws[c4 * 4 + 3][lane] = w.w;
  }
  __syncthreads();

  int tx = tid & 15;   // output col quad
  int ty = tid >> 4;   // output row quad
  float acc[4][4] = {{0.f}};

#pragma unroll 8
  for (int k = 0; k < 128; ++k) {
    float4 av = *reinterpret_cast<const float4*>(&Xs[k][4 * ty]);
    float4 bv = *reinterpret_cast<const float4*>(&Ws[k][4 * tx]);
    float ar[4] = {av.x, av.y, av.z, av.w};
    float br[4] = {bv.x, bv.y, bv.z, bv.w};
#pragma unroll
    for (int i = 0; i < 4; ++i)
#pragma unroll
      for (int j = 0; j < 4; ++j) acc[i][j] += ar[i] * br[j];
  }

  float4 bb = *reinterpret_cast<const float4*>(bias + bcol0 + 4 * tx);
  float br[4] = {bb.x, bb.y, bb.z, bb.w};
#pragma unroll
  for (int i = 0; i < 4; ++i) {
    float4 o;
    o.x = fmaxf(acc[i][0] + br[0], 0.f);
    o.y = fmaxf(acc[i][1] + br[1], 0.f);
    o.z = fmaxf(acc[i][2] + br[2], 0.f);
    o.w = fmaxf(acc[i][3] + br[3], 0.f);
    *reinterpret_cast<float4*>(out + (size_t)(brow0 + 4 * ty + i) * Fdim + bcol0 + 4 * tx) = o;
  }
}

extern "C" void kernel_launch(void* const* d_in, const int* in_sizes, int n_in,
                              void* d_out, int out_size, void* d_ws, size_t ws_size,
                              hipStream_t stream) {
  const int* inputs = (const int*)d_in[0];    // [B]
  const int* nbr = (const int*)d_in[1];       // [N,16]
  const float* emb = (const float*)d_in[2];   // [N,128]
  const float* W = (const float*)d_in[3];     // [F,128]
  const float* bias = (const float*)d_in[4];  // [F]
  float* out = (float*)d_out;

  const int B = in_sizes[0];
  const int N = in_sizes[2] / EDIM;
  const int F = in_sizes[4];

  float* h1 = (float*)d_ws;                      // N*128 floats
  float* X = h1 + (size_t)N * EDIM;              // B*128 floats

  hop_mean_kernel<<<dim3((N + 7) / 8), 256, 0, stream>>>(nbr, emb, h1, N);
  gather2_kernel<<<dim3((B + 7) / 8), 256, 0, stream>>>(inputs, nbr, h1, emb, X, B);
  gemm_relu_kernel<<<dim3(B / 64, F / 64), 256, 0, stream>>>(X, W, bias, out, F);
}

// Round 2
// 95.600 us; speedup vs baseline: 1.6938x; 1.6938x over previous
//
#include <hip/hip_runtime.h>
#include <hip/hip_bf16.h>

#define EDIM 128

typedef __attribute__((ext_vector_type(4))) float f32x4;
typedef __attribute__((ext_vector_type(8))) short bf16x8;

// ---- helpers ---------------------------------------------------------------
__device__ __forceinline__ unsigned pack_bf16(float lo, float hi) {
  __hip_bfloat16 l = __float2bfloat16(lo);
  __hip_bfloat16 h = __float2bfloat16(hi);
  unsigned short lu = *reinterpret_cast<unsigned short*>(&l);
  unsigned short hu = *reinterpret_cast<unsigned short*>(&h);
  return (unsigned)lu | ((unsigned)hu << 16);
}
__device__ __forceinline__ float bf_lo(unsigned u) { return __uint_as_float(u << 16); }
__device__ __forceinline__ float bf_hi(unsigned u) { return __uint_as_float(u & 0xffff0000u); }

// ---------------------------------------------------------------------------
// K0: fp32 -> bf16 conversion (8 elements / thread, grid-stride)
// ---------------------------------------------------------------------------
__global__ __launch_bounds__(256) void convert_bf16_kernel(
    const float* __restrict__ src, unsigned short* __restrict__ dst, int n8) {
  for (int i = blockIdx.x * 256 + threadIdx.x; i < n8; i += gridDim.x * 256) {
    const float4* s4 = reinterpret_cast<const float4*>(src) + (size_t)i * 2;
    float4 a = s4[0], b = s4[1];
    uint4 o;
    o.x = pack_bf16(a.x, a.y);
    o.y = pack_bf16(a.z, a.w);
    o.z = pack_bf16(b.x, b.y);
    o.w = pack_bf16(b.z, b.w);
    *(reinterpret_cast<uint4*>(dst) + i) = o;
  }
}

// ---------------------------------------------------------------------------
// K1: h1_bf16[n] = mean over 16 neighbors of emb_bf16[nbr].
// 16 lanes/node (16B = 8 bf16 per lane), 16 nodes/block. fp32 accumulate.
// ---------------------------------------------------------------------------
__global__ __launch_bounds__(256) void hop1_kernel(
    const int* __restrict__ nbr, const unsigned short* __restrict__ src,
    unsigned short* __restrict__ dst, int nNodes) {
  int node = blockIdx.x * 16 + (threadIdx.x >> 4);
  if (node >= nNodes) return;
  int lane = threadIdx.x & 15;

  const int4* nb4 = reinterpret_cast<const int4*>(nbr) + (size_t)node * 4;
  int4 a = nb4[0], b = nb4[1], c = nb4[2], d = nb4[3];
  int idx[16] = {a.x, a.y, a.z, a.w, b.x, b.y, b.z, b.w,
                 c.x, c.y, c.z, c.w, d.x, d.y, d.z, d.w};

  float acc[8] = {0.f, 0.f, 0.f, 0.f, 0.f, 0.f, 0.f, 0.f};
#pragma unroll
  for (int m = 0; m < 16; ++m) {
    uint4 v = *reinterpret_cast<const uint4*>(src + (size_t)idx[m] * EDIM + lane * 8);
    acc[0] += bf_lo(v.x); acc[1] += bf_hi(v.x);
    acc[2] += bf_lo(v.y); acc[3] += bf_hi(v.y);
    acc[4] += bf_lo(v.z); acc[5] += bf_hi(v.z);
    acc[6] += bf_lo(v.w); acc[7] += bf_hi(v.w);
  }
  uint4 o;
  o.x = pack_bf16(acc[0] * 0.0625f, acc[1] * 0.0625f);
  o.y = pack_bf16(acc[2] * 0.0625f, acc[3] * 0.0625f);
  o.z = pack_bf16(acc[4] * 0.0625f, acc[5] * 0.0625f);
  o.w = pack_bf16(acc[6] * 0.0625f, acc[7] * 0.0625f);
  *reinterpret_cast<uint4*>(dst + (size_t)node * EDIM + lane * 8) = o;
}

// ---------------------------------------------------------------------------
// K2: X_bf16[b] = mean16(h1_bf16[nbr[inputs[b]]]) + emb_bf16[inputs[b]]
// ---------------------------------------------------------------------------
__global__ __launch_bounds__(256) void hop2_kernel(
    const int* __restrict__ inputs, const int* __restrict__ nbr,
    const unsigned short* __restrict__ h1, const unsigned short* __restrict__ embb,
    unsigned short* __restrict__ X, int Bn) {
  int b = blockIdx.x * 16 + (threadIdx.x >> 4);
  if (b >= Bn) return;
  int lane = threadIdx.x & 15;
  int node = inputs[b];

  const int4* nb4 = reinterpret_cast<const int4*>(nbr) + (size_t)node * 4;
  int4 aa = nb4[0], bb = nb4[1], cc = nb4[2], dd = nb4[3];
  int idx[16] = {aa.x, aa.y, aa.z, aa.w, bb.x, bb.y, bb.z, bb.w,
                 cc.x, cc.y, cc.z, cc.w, dd.x, dd.y, dd.z, dd.w};

  float acc[8] = {0.f, 0.f, 0.f, 0.f, 0.f, 0.f, 0.f, 0.f};
#pragma unroll
  for (int m = 0; m < 16; ++m) {
    uint4 v = *reinterpret_cast<const uint4*>(h1 + (size_t)idx[m] * EDIM + lane * 8);
    acc[0] += bf_lo(v.x); acc[1] += bf_hi(v.x);
    acc[2] += bf_lo(v.y); acc[3] += bf_hi(v.y);
    acc[4] += bf_lo(v.z); acc[5] += bf_hi(v.z);
    acc[6] += bf_lo(v.w); acc[7] += bf_hi(v.w);
  }
  uint4 se = *reinterpret_cast<const uint4*>(embb + (size_t)node * EDIM + lane * 8);
  uint4 o;
  o.x = pack_bf16(acc[0] * 0.0625f + bf_lo(se.x), acc[1] * 0.0625f + bf_hi(se.x));
  o.y = pack_bf16(acc[2] * 0.0625f + bf_lo(se.y), acc[3] * 0.0625f + bf_hi(se.y));
  o.z = pack_bf16(acc[4] * 0.0625f + bf_lo(se.z), acc[5] * 0.0625f + bf_hi(se.z));
  o.w = pack_bf16(acc[6] * 0.0625f + bf_lo(se.w), acc[7] * 0.0625f + bf_hi(se.w));
  *reinterpret_cast<uint4*>(X + (size_t)b * EDIM + lane * 8) = o;
}

// ---------------------------------------------------------------------------
// K3: out = relu(X @ W^T + bias) via mfma_f32_16x16x32_bf16.
// X:[B,128] bf16, W:[F,128] bf16 (row-major = B^T layout -> A/B frag loads
// are symmetric). One wave per 16 rows, sweeping all F columns.
// C/D layout: col = lane&15, row = (lane>>4)*4 + reg   [m89-verified]
// A/B frag:   row/col = lane&15, k = (lane>>4)*8 + i
// ---------------------------------------------------------------------------
__global__ __launch_bounds__(256) void gemm_mfma_kernel(
    const unsigned short* __restrict__ X, const unsigned short* __restrict__ Wb,
    const float* __restrict__ bias, float* __restrict__ out, int Fdim) {
  int wave = (blockIdx.x * 256 + threadIdx.x) >> 6;
  int lane = threadIdx.x & 63;
  int row0 = wave * 16;
  int r = lane & 15;
  int half = lane >> 4;  // 0..3

  bf16x8 afrag[4];
#pragma unroll
  for (int kk = 0; kk < 4; ++kk) {
    uint4 v = *reinterpret_cast<const uint4*>(
        X + (size_t)(row0 + r) * EDIM + kk * 32 + half * 8);
    afrag[kk] = *reinterpret_cast<bf16x8*>(&v);
  }

  for (int c0 = 0; c0 < Fdim; c0 += 16) {
    f32x4 acc = {0.f, 0.f, 0.f, 0.f};
#pragma unroll
    for (int kk = 0; kk < 4; ++kk) {
      uint4 w = *reinterpret_cast<const uint4*>(
          Wb + (size_t)(c0 + r) * EDIM + kk * 32 + half * 8);
      bf16x8 bfrag = *reinterpret_cast<bf16x8*>(&w);
      acc = __builtin_amdgcn_mfma_f32_16x16x32_bf16(afrag[kk], bfrag, acc, 0, 0, 0);
    }
    float bv = bias[c0 + r];
#pragma unroll
    for (int reg = 0; reg < 4; ++reg) {
      out[(size_t)(row0 + half * 4 + reg) * Fdim + c0 + r] =
          fmaxf(acc[reg] + bv, 0.f);
    }
  }
}

// ---------------------------------------------------------------------------
extern "C" void kernel_launch(void* const* d_in, const int* in_sizes, int n_in,
                              void* d_out, int out_size, void* d_ws, size_t ws_size,
                              hipStream_t stream) {
  const int* inputs = (const int*)d_in[0];    // [B]
  const int* nbr = (const int*)d_in[1];       // [N,16]
  const float* emb = (const float*)d_in[2];   // [N,128]
  const float* W = (const float*)d_in[3];     // [F,128]
  const float* bias = (const float*)d_in[4];  // [F]
  float* out = (float*)d_out;

  const int B = in_sizes[0];
  const int N = in_sizes[2] / EDIM;
  const int F = in_sizes[4];

  unsigned short* embb = (unsigned short*)d_ws;          // N*128 bf16
  unsigned short* h1 = embb + (size_t)N * EDIM;          // N*128 bf16
  unsigned short* Wb = h1 + (size_t)N * EDIM;            // F*128 bf16
  unsigned short* X = Wb + (size_t)F * EDIM;             // B*128 bf16

  // K0: convert emb and W to bf16
  int n8_emb = N * EDIM / 8;
  convert_bf16_kernel<<<2048, 256, 0, stream>>>(emb, embb, n8_emb);
  int n8_w = F * EDIM / 8;
  convert_bf16_kernel<<<(n8_w + 255) / 256, 256, 0, stream>>>(W, Wb, n8_w);

  // K1: hop 1 over all nodes
  hop1_kernel<<<(N + 15) / 16, 256, 0, stream>>>(nbr, embb, h1, N);

  // K2: hop 2 at query nodes + self embedding, pack X
  hop2_kernel<<<(B + 15) / 16, 256, 0, stream>>>(inputs, nbr, h1, embb, X, B);

  // K3: fused GEMM + bias + relu
  int waves = B / 16;
  gemm_mfma_kernel<<<waves / 4, 256, 0, stream>>>(X, Wb, bias, out, F);
}